// Round 1
// baseline (640.979 us; speedup 1.0000x reference)
//
#include <hip/hip_runtime.h>

#define D 2048
#define KPAD 160
#define PSTR 168
#define MTILE 16
#define THREADS 512

typedef __attribute__((ext_vector_type(8))) short bf16x8;
typedef __attribute__((ext_vector_type(4))) float f32x4;

__device__ inline unsigned short f2bf(float f) {
  unsigned int u = __float_as_uint(f);
  u += 0x7fffu + ((u >> 16) & 1u);   // round-to-nearest-even
  return (unsigned short)(u >> 16);
}

// ---- prep: pack Wp|Wv -> Wpv_t[32][2048] bf16 (n-major, k contiguous) ----
__global__ __launch_bounds__(256) void prep_wpv(const float* __restrict__ Wp,
                                                const float* __restrict__ Wv,
                                                unsigned short* __restrict__ Wpvt) {
  int idx = blockIdx.x * 256 + threadIdx.x;   // 32*2048 elements
  int n = idx >> 11, k = idx & 2047;
  float v = 0.f;
  if (n < 12) v = Wp[k * 12 + n];
  else if (n < 24) v = Wv[k * 12 + (n - 12)];
  Wpvt[idx] = f2bf(v);
}

// ---- prep: Wi[144][2048] -> Wi_t[2048][160] bf16 (n-major, k contiguous, K padded) ----
__global__ __launch_bounds__(256) void prep_wi(const float* __restrict__ Wi,
                                               unsigned short* __restrict__ Wit) {
  int idx = blockIdx.x * 256 + threadIdx.x;   // 2048*160 elements
  int n = idx / KPAD, k = idx - n * KPAD;
  float v = (k < 144) ? Wi[k * 2048 + n] : 0.f;
  Wit[idx] = f2bf(v);
}

// ---- fused: pos/vel -> outer -> @Wi (transposed) -> residual -> LayerNorm ----
// LDS: sred 18432 + sP 5376 + spart 1024 + sstat 128 = 24960 B.
__global__ __launch_bounds__(THREADS, 4) void gil_fused(
    const float* __restrict__ x, const float* __restrict__ bp,
    const float* __restrict__ bv, const float* __restrict__ bi,
    const float* __restrict__ gamma, const float* __restrict__ beta,
    const unsigned short* __restrict__ Wpvt, const unsigned short* __restrict__ Wit,
    float* __restrict__ out) {
  __shared__ float sred[8][MTILE][36];                    // pad 36: 2-way max on write/read
  __shared__ __align__(16) unsigned short sP[MTILE][PSTR];
  __shared__ float spart[8][MTILE][2];
  __shared__ float sstat[MTILE][2];

  const int t = threadIdx.x;
  const int rowbase = blockIdx.x * MTILE;
  const int wave = t >> 6, lane = t & 63;
  const int lm = lane & 15, quad = lane >> 4;

  // ---- phase 1: pos|vel = x @ Wpv; each wave owns K-slice of 256, both n-tiles.
  //      x read straight global->frag (f32->bf16 in reg); x touched exactly once here.
  {
    const float* xr = x + (size_t)(rowbase + lm) * D + wave * 256;
    const unsigned short* b0 = Wpvt + (size_t)lm * D + wave * 256;
    const unsigned short* b1 = Wpvt + (size_t)(16 + lm) * D + wave * 256;
    f32x4 acc0 = {0.f, 0.f, 0.f, 0.f}, acc1 = {0.f, 0.f, 0.f, 0.f};
#pragma unroll
    for (int kk = 0; kk < 8; ++kk) {
      int k0 = kk * 32 + quad * 8;
      f32x4 v0 = *(const f32x4*)(xr + k0);
      f32x4 v1 = *(const f32x4*)(xr + k0 + 4);
      bf16x8 a;
#pragma unroll
      for (int e = 0; e < 4; ++e) {
        a[e]     = (short)f2bf(v0[e]);
        a[4 + e] = (short)f2bf(v1[e]);
      }
      bf16x8 w0 = *(const bf16x8*)(b0 + k0);
      bf16x8 w1 = *(const bf16x8*)(b1 + k0);
      acc0 = __builtin_amdgcn_mfma_f32_16x16x32_bf16(a, w0, acc0, 0, 0, 0);
      acc1 = __builtin_amdgcn_mfma_f32_16x16x32_bf16(a, w1, acc1, 0, 0, 0);
    }
#pragma unroll
    for (int rg = 0; rg < 4; ++rg) {
      sred[wave][quad * 4 + rg][lm]      = acc0[rg];
      sred[wave][quad * 4 + rg][16 + lm] = acc1[rg];
    }
  }
  __syncthreads();

  // ---- phase 1b: 8-way K-reduce + bias, outer product via shuffles -> sP bf16 ----
  {
    int m = t >> 5, n = t & 31;
    float pv = 0.f;
#pragma unroll
    for (int w = 0; w < 8; ++w) pv += sred[w][m][n];
    if (n < 12) pv += bp[n];
    else if (n < 24) pv += bv[n - 12];
#pragma unroll
    for (int kk = 0; kk < 5; ++kk) {
      int k = n + 32 * kk;
      int i = k / 12, j = k - i * 12;
      float a = __shfl(pv, i, 32);
      float b = __shfl(pv, 12 + j, 32);
      sP[m][k] = f2bf((k < 144) ? a * b : 0.f);
    }
  }
  __syncthreads();

  // ---- phase 2: inter^T = Wi_rows x P  (operands swapped -> lane owns 4 consecutive d) ----
  // acc[rg] = inter[row = lm][d = wave*256 + nt*16 + quad*4 + rg]
  f32x4 accv[16];
  {
    bf16x8 bf[5];
#pragma unroll
    for (int kc = 0; kc < 5; ++kc)
      bf[kc] = *(const bf16x8*)&sP[lm][kc * 32 + quad * 8];
#pragma unroll
    for (int nt = 0; nt < 16; ++nt) {
      const unsigned short* wb = Wit + (size_t)(wave * 256 + nt * 16 + lm) * KPAD;
      f32x4 acc = {0.f, 0.f, 0.f, 0.f};
#pragma unroll
      for (int kc = 0; kc < 5; ++kc) {
        bf16x8 wv = *(const bf16x8*)(wb + kc * 32 + quad * 8);
        acc = __builtin_amdgcn_mfma_f32_16x16x32_bf16(wv, bf[kc], acc, 0, 0, 0);
      }
      accv[nt] = acc;
    }
  }

  // ---- phase 3a: y = x + inter + bi (exact f32 x, float4/lane); per-lane LN partials ----
  float s = 0.f, ss = 0.f;
  {
    const float* xrow = x + (size_t)(rowbase + lm) * D;
#pragma unroll
    for (int nt = 0; nt < 16; ++nt) {
      int d0 = wave * 256 + nt * 16 + quad * 4;
      f32x4 bi4 = *(const f32x4*)(bi + d0);
      f32x4 x4  = *(const f32x4*)(xrow + d0);
#pragma unroll
      for (int rg = 0; rg < 4; ++rg) {
        float y = accv[nt][rg] + bi4[rg] + x4[rg];
        accv[nt][rg] = y;
        s += y;
        ss += y * y;
      }
    }
    // combine the 4 quads that share row lm
    s += __shfl_xor(s, 16); ss += __shfl_xor(ss, 16);
    s += __shfl_xor(s, 32); ss += __shfl_xor(ss, 32);
    if (lane < 16) { spart[wave][lm][0] = s; spart[wave][lm][1] = ss; }
  }
  __syncthreads();
  if (t < MTILE) {
    float su = 0.f, sq = 0.f;
#pragma unroll
    for (int w = 0; w < 8; ++w) { su += spart[w][t][0]; sq += spart[w][t][1]; }
    float mu = su * (1.f / D);
    float var = sq * (1.f / D) - mu * mu;
    sstat[t][0] = mu;
    sstat[t][1] = rsqrtf(var + 1e-5f);
  }
  __syncthreads();

  // ---- phase 3b: normalize + float4 stores ----
  {
    float mu = sstat[lm][0], rs = sstat[lm][1];
    float* orow = out + (size_t)(rowbase + lm) * D;
#pragma unroll
    for (int nt = 0; nt < 16; ++nt) {
      int d0 = wave * 256 + nt * 16 + quad * 4;
      f32x4 g4  = *(const f32x4*)(gamma + d0);
      f32x4 be4 = *(const f32x4*)(beta + d0);
      f32x4 o;
#pragma unroll
      for (int rg = 0; rg < 4; ++rg)
        o[rg] = (accv[nt][rg] - mu) * rs * g4[rg] + be4[rg];
      *(f32x4*)(orow + d0) = o;
    }
  }
}

extern "C" void kernel_launch(void* const* d_in, const int* in_sizes, int n_in,
                              void* d_out, int out_size, void* d_ws, size_t ws_size,
                              hipStream_t stream) {
  const float* x     = (const float*)d_in[0];
  const float* Wp    = (const float*)d_in[1];
  const float* bp    = (const float*)d_in[2];
  const float* Wv    = (const float*)d_in[3];
  const float* bv    = (const float*)d_in[4];
  const float* Wi    = (const float*)d_in[5];
  const float* bi    = (const float*)d_in[6];
  const float* gamma = (const float*)d_in[7];
  const float* beta  = (const float*)d_in[8];
  float* out = (float*)d_out;

  unsigned short* Wpvt = (unsigned short*)d_ws;               // 32*2048 bf16
  unsigned short* Wit  = Wpvt + 32 * 2048;                    // 2048*160 bf16

  prep_wpv<<<(32 * 2048) / 256, 256, 0, stream>>>(Wp, Wv, Wpvt);
  prep_wi<<<(2048 * KPAD) / 256, 256, 0, stream>>>(Wi, Wit);

  int rows = in_sizes[0] / D;                                  // 32768
  gil_fused<<<rows / MTILE, THREADS, 0, stream>>>(x, bp, bv, bi, gamma, beta,
                                                  Wpvt, Wit, out);
}